// Round 1
// baseline (270.306 us; speedup 1.0000x reference)
//
#include <hip/hip_runtime.h>
#include <hip/hip_bf16.h>

// Embedding gather: out[b,s,:] = w[x[b,s],:]
// x: (8,2048) int32 = 16384 tokens; w: (50257,1024) fp32; out fp32.
// One block per token, 256 threads, each thread copies one float4
// (1024 floats/row = 256 float4). Row base is wave-uniform (scalar),
// lanes stride 16B -> fully coalesced 4KiB segments read and write.

#define DIM_F4 256  // 1024 floats / 4

__global__ __launch_bounds__(256) void emb_gather_kernel(
    const int* __restrict__ x,
    const float4* __restrict__ w,
    float4* __restrict__ out) {
    const int row = blockIdx.x;          // token index [0, 16384)
    const int idx = x[row];              // uniform per block -> scalar load
    const int t = threadIdx.x;           // [0, 256)
    out[(size_t)row * DIM_F4 + t] = w[(size_t)idx * DIM_F4 + t];
}

extern "C" void kernel_launch(void* const* d_in, const int* in_sizes, int n_in,
                              void* d_out, int out_size, void* d_ws, size_t ws_size,
                              hipStream_t stream) {
    const int* x = (const int*)d_in[0];          // 16384 indices
    const float4* w = (const float4*)d_in[1];    // 50257*1024 fp32
    float4* out = (float4*)d_out;                // 16384*1024 fp32

    const int n_tokens = in_sizes[0];            // 16384
    emb_gather_kernel<<<n_tokens, 256, 0, stream>>>(x, w, out);
}

// Round 3
// 269.765 us; speedup vs baseline: 1.0020x; 1.0020x over previous
//
#include <hip/hip_runtime.h>
#include <hip/hip_bf16.h>

// Embedding gather: out[b,s,:] = w[x[b,s],:]
// x: (8,2048) int32 = 16384 tokens; w: (50257,1024) fp32; out fp32.
//
// R3: same structure as R2 but with clang-native float4 vectors
// (__builtin_nontemporal_store rejects HIP_vector_type). 8 rows per block
// (2048 blocks x 256 threads); 8 uniform index preloads (scalarized), then
// 8 independent 16B loads in flight per thread, then 8 non-temporal
// streaming stores (out is write-once -- keep L2/L3 capacity for w).

typedef float nf4 __attribute__((ext_vector_type(4)));  // native 16B vector

#define DIM_F4 256        // 1024 floats / 4 per row
#define ROWS_PER_BLOCK 8

__global__ __launch_bounds__(256) void emb_gather_kernel(
    const int* __restrict__ x,
    const nf4* __restrict__ w,
    nf4* __restrict__ out) {
    const int base = blockIdx.x * ROWS_PER_BLOCK;   // first token of this block
    const int t = threadIdx.x;                      // [0,256): float4 slot in row

    // Uniform index preload (base+i is wave-uniform -> scalar loads).
    int idx[ROWS_PER_BLOCK];
#pragma unroll
    for (int i = 0; i < ROWS_PER_BLOCK; ++i)
        idx[i] = x[base + i];

    // 8 independent gathers in flight per thread (128 B outstanding).
    nf4 v[ROWS_PER_BLOCK];
#pragma unroll
    for (int i = 0; i < ROWS_PER_BLOCK; ++i)
        v[i] = w[(size_t)idx[i] * DIM_F4 + t];

    // Streaming (non-temporal) coalesced stores.
#pragma unroll
    for (int i = 0; i < ROWS_PER_BLOCK; ++i)
        __builtin_nontemporal_store(v[i], &out[(size_t)(base + i) * DIM_F4 + t]);
}

extern "C" void kernel_launch(void* const* d_in, const int* in_sizes, int n_in,
                              void* d_out, int out_size, void* d_ws, size_t ws_size,
                              hipStream_t stream) {
    const int* x = (const int*)d_in[0];          // 16384 indices
    const nf4* w = (const nf4*)d_in[1];          // 50257*1024 fp32
    nf4* out = (nf4*)d_out;                      // 16384*1024 fp32

    const int n_tokens = in_sizes[0];            // 16384, divisible by 8
    const int blocks = n_tokens / ROWS_PER_BLOCK;
    emb_gather_kernel<<<blocks, 256, 0, stream>>>(x, w, out);
}